// Round 3
// baseline (12446.935 us; speedup 1.0000x reference)
//
#include <hip/hip_runtime.h>

// ---------------- problem dims ----------------
#define N_SEQ 64
#define T_LEN 512
#define IN_SZ 512
#define HID   1024
#define ODIM  256

// ---------------- config ----------------
#define REC_WGS  128
#define PROJ_WGS 16
#define TOT_WGS  (REC_WGS + PROJ_WGS)
#define BLK      512

// ---------------- ws layout (bytes) ----------------
#define CNT_OFF  0                 // u32 cnt[2][512] arrive counters
#define HBUF_OFF 4096              // 8-slot ring of [64][1024] fp16
#define HSLOT    (N_SEQ * HID)     // halves per slot (65536)

// ---------------- rec LDS layout (bytes) ----------------
#define WF_OFF   0                 // 96 frags x 1024 B (frag-major weights)
#define CB_OFF   98304             // cbuf: [nb][kq-1][slot] x 4096 B (12 bufs)
#define GB_OFF   147456            // gbuf: [nb] x 4096 B
#define BIAS_OFF 155648            // 32 f32
#define FLG_OFF  155776            // lflg[2][4] u32
#define DONE_OFF 155808            // ldone[2] int
#define LDS_BYTES 155904
// proj overlay
#define PW_OFF 0                   // 32 frags x 1024 B
#define PB_OFF 32768               // 16 f32

typedef _Float16 half8  __attribute__((ext_vector_type(8)));
typedef float    f32x4  __attribute__((ext_vector_type(4)));
typedef float    f32x16 __attribute__((ext_vector_type(16)));

union U16B { unsigned long long u[2]; half8 h; };
union U8B  { _Float16 h[4]; unsigned long long u; };

__device__ __forceinline__ float sigmf(float x) { return 1.f / (1.f + expf(-x)); }

// init: zero counters, hb ring slot 7 <- fp16(h0)
__global__ void init_kernel(const float* __restrict__ h0, unsigned char* __restrict__ ws) {
  int idx = blockIdx.x * 256 + threadIdx.x;
  if (idx < 1024) ((unsigned*)ws)[idx] = 0u;   // 4 KB cnt region
  _Float16* h7 = (_Float16*)(ws + HBUF_OFF) + (size_t)7 * HSLOT;
  for (int i = idx; i < N_SEQ * HID; i += gridDim.x * 256) h7[i] = (_Float16)h0[i];
}

__launch_bounds__(BLK, 1)
__global__ void lstm_coop(const float* __restrict__ obs,
                          const float* __restrict__ c0,
                          const float* __restrict__ es,
                          const float* __restrict__ W_ih,
                          const float* __restrict__ W_hh,
                          const float* __restrict__ b_ih,
                          const float* __restrict__ b_hh,
                          const float* __restrict__ W_proj,
                          const float* __restrict__ b_proj,
                          float* __restrict__ out,
                          unsigned char* __restrict__ ws) {
  extern __shared__ char smem[];
  const int tid = threadIdx.x, bid = blockIdx.x;
  const int w = tid >> 6, lane = tid & 63;
  unsigned* cnt = (unsigned*)(ws + CNT_OFF);
  _Float16* hb = (_Float16*)(ws + HBUF_OFF);

  if (bid < REC_WGS) {
    // ============== recurrent role ==============
    _Float16* wf  = (_Float16*)(smem + WF_OFF);
    float* cb     = (float*)(smem + CB_OFF);
    float* gb     = (float*)(smem + GB_OFF);
    float* bias   = (float*)(smem + BIAS_OFF);
    unsigned* lflg= (unsigned*)(smem + FLG_OFF);
    int* ldone    = (int*)(smem + DONE_OFF);

    // stage weights frag-major: frag f (virtual k = f*16), lane l holds
    // B[col = l&31][k = f*16 + (l>>5)*8 + j], contiguous 16 B per lane.
    for (int idx = tid; idx < 96 * 64; idx += BLK) {
      int f = idx >> 6, l = idx & 63;
      int c = l & 31, kg = (l >> 5) * 8;
      int vk = f * 16 + kg;
      int grow = (c >> 3) * HID + bid * 8 + (c & 7);   // gate-major row in 4H
      _Float16* dst = wf + f * 512 + l * 8;
      if (vk < IN_SZ) {
        const float* src = W_ih + (size_t)grow * IN_SZ + vk;
        #pragma unroll
        for (int j = 0; j < 8; ++j) dst[j] = (_Float16)src[j];
      } else {
        const float* src = W_hh + (size_t)grow * HID + (vk - IN_SZ);
        #pragma unroll
        for (int j = 0; j < 8; ++j) dst[j] = (_Float16)src[j];
      }
    }
    if (tid < 32) {
      int grow = (tid >> 3) * HID + bid * 8 + (tid & 7);
      bias[tid] = b_ih[grow] + b_hh[grow];
    }
    if (tid < 8) lflg[tid] = 0u;
    if (tid < 2) ldone[tid] = -1;
    __syncthreads();

    const int nb = w & 1;      // sequence block (32 seqs)
    const int kq = w >> 1;     // 0 = combiner, 1 = x, 2/3 = h halves

    if (kq == 0) {
      // ---------- combiner / epilogue wave ----------
      const int row = lane & 31;
      const int hi  = (row >> 2) & 1;
      const int r_  = (row & 3) + 4 * (row >> 3);
      const int jb  = (lane >> 5) * 4;
      const int n   = nb * 32 + row;
      const int hcb = bid * 8 + jb;
      float cs[4], bb[4][4];
      #pragma unroll
      for (int p = 0; p < 4; ++p) {
        cs[p] = c0[(size_t)n * HID + hcb + p];
        #pragma unroll
        for (int g = 0; g < 4; ++g) bb[g][p] = bias[g * 8 + jb + p];
      }
      float* gbn = gb + nb * 1024;

      for (int t = 0; t < T_LEN; ++t) {
        if (lane == 0) {
          while (__hip_atomic_load(&lflg[nb * 4 + (t & 3)], __ATOMIC_ACQUIRE,
                                   __HIP_MEMORY_SCOPE_WORKGROUP) < 3u)
            __builtin_amdgcn_s_sleep(1);
          __hip_atomic_store(&lflg[nb * 4 + (t & 3)], 0u, __ATOMIC_RELAXED,
                             __HIP_MEMORY_SCOPE_WORKGROUP);
        }
        __asm__ volatile("" ::: "memory");

        // sum 3 partial buffers
        f32x4 s0 = {}, s1 = {}, s2 = {}, s3 = {};
        #pragma unroll
        for (int i = 0; i < 3; ++i) {
          const float* b = cb + (((nb * 3 + i) * 2) + (t & 1)) * 1024 + lane * 16;
          s0 += *(const f32x4*)(b + 0);
          s1 += *(const f32x4*)(b + 4);
          s2 += *(const f32x4*)(b + 8);
          s3 += *(const f32x4*)(b + 12);
        }
        if (lane == 0)
          __hip_atomic_store(&ldone[nb], t, __ATOMIC_RELEASE,
                             __HIP_MEMORY_SCOPE_WORKGROUP);

        // transpose via gbuf: write C-frag layout, gather per (row, hcol)
        *(f32x4*)(gbn + lane * 16 + 0)  = s0;
        *(f32x4*)(gbn + lane * 16 + 4)  = s1;
        *(f32x4*)(gbn + lane * 16 + 8)  = s2;
        *(f32x4*)(gbn + lane * 16 + 12) = s3;
        __asm__ volatile("s_waitcnt lgkmcnt(0)" ::: "memory");

        float m = 1.f - es[(size_t)n * T_LEN + t];
        U8B pk;
        #pragma unroll
        for (int p = 0; p < 4; ++p) {
          int j = jb + p;
          float pi = gbn[((0 * 8 + j) + 32 * hi) * 16 + r_] + bb[0][p];
          float pf = gbn[((1 * 8 + j) + 32 * hi) * 16 + r_] + bb[1][p];
          float pg = gbn[((2 * 8 + j) + 32 * hi) * 16 + r_] + bb[2][p];
          float po = gbn[((3 * 8 + j) + 32 * hi) * 16 + r_] + bb[3][p];
          float cv = sigmf(pf) * (cs[p] * m) + sigmf(pi) * tanhf(pg);
          cs[p] = cv;
          pk.h[p] = (_Float16)(sigmf(po) * tanhf(cv));
        }
        __hip_atomic_store(
            (unsigned long long*)(hb + (size_t)(t & 7) * HSLOT + (size_t)n * HID + hcb),
            pk.u, __ATOMIC_RELAXED, __HIP_MEMORY_SCOPE_AGENT);
        __asm__ volatile("s_waitcnt vmcnt(0)" ::: "memory");
        if (lane == 0)
          __hip_atomic_fetch_add(&cnt[nb * T_LEN + t], 1u, __ATOMIC_RELAXED,
                                 __HIP_MEMORY_SCOPE_AGENT);
      }
    } else {
      // ---------- GEMM writer waves ----------
      const int row = lane & 31, kg = (lane >> 5) * 8;
      const int n = nb * 32 + row;
      const int fbase = (kq - 1) * 32;

      for (int t = 0; t < T_LEN; ++t) {
        if (lane == 0) {
          if (t >= 2)
            while (__hip_atomic_load(&ldone[nb], __ATOMIC_ACQUIRE,
                                     __HIP_MEMORY_SCOPE_WORKGROUP) < t - 1)
              __builtin_amdgcn_s_sleep(1);
          if (kq >= 2 && t >= 1)
            while (__hip_atomic_load(&cnt[nb * T_LEN + t - 1], __ATOMIC_RELAXED,
                                     __HIP_MEMORY_SCOPE_AGENT) < (unsigned)REC_WGS)
              __builtin_amdgcn_s_sleep(2);
        }
        __asm__ volatile("" ::: "memory");

        f32x16 acc = {};
        if (kq == 1) {
          // x part, K=512, fp32->fp16 inline
          const float* xr = obs + ((size_t)n * T_LEN + t) * IN_SZ + kg;
          #pragma unroll 8
          for (int i = 0; i < 32; ++i) {
            f32x4 v0 = *(const f32x4*)(xr + i * 16);
            f32x4 v1 = *(const f32x4*)(xr + i * 16 + 4);
            half8 a;
            a[0] = (_Float16)v0[0]; a[1] = (_Float16)v0[1];
            a[2] = (_Float16)v0[2]; a[3] = (_Float16)v0[3];
            a[4] = (_Float16)v1[0]; a[5] = (_Float16)v1[1];
            a[6] = (_Float16)v1[2]; a[7] = (_Float16)v1[3];
            half8 b = *(const half8*)(wf + i * 512 + lane * 8);
            acc = __builtin_amdgcn_mfma_f32_32x32x16_f16(a, b, acc, 0, 0, 0);
          }
        } else {
          // h part, K=512 half, sc1 loads from ring slot t-1
          float esv = es[(size_t)n * T_LEN + t];
          bool kill = (esv != 0.f);
          const _Float16* hr = hb + (size_t)((t + 7) & 7) * HSLOT +
                               (size_t)n * HID + (kq - 2) * 512 + kg;
          #pragma unroll 8
          for (int i = 0; i < 32; ++i) {
            U16B u;
            u.u[0] = __hip_atomic_load((const unsigned long long*)(hr + i * 16),
                                       __ATOMIC_RELAXED, __HIP_MEMORY_SCOPE_AGENT);
            u.u[1] = __hip_atomic_load((const unsigned long long*)(hr + i * 16 + 4),
                                       __ATOMIC_RELAXED, __HIP_MEMORY_SCOPE_AGENT);
            half8 a = u.h;
            if (kill) a = (half8){};
            half8 b = *(const half8*)(wf + (fbase + i) * 512 + lane * 8);
            acc = __builtin_amdgcn_mfma_f32_32x32x16_f16(a, b, acc, 0, 0, 0);
          }
        }
        float* mycb = cb + (((nb * 3 + (kq - 1)) * 2) + (t & 1)) * 1024 + lane * 16;
        *(f32x4*)(mycb + 0)  = (f32x4){acc[0], acc[1], acc[2], acc[3]};
        *(f32x4*)(mycb + 4)  = (f32x4){acc[4], acc[5], acc[6], acc[7]};
        *(f32x4*)(mycb + 8)  = (f32x4){acc[8], acc[9], acc[10], acc[11]};
        *(f32x4*)(mycb + 12) = (f32x4){acc[12], acc[13], acc[14], acc[15]};
        if (lane == 0)
          __hip_atomic_fetch_add(&lflg[nb * 4 + (t & 3)], 1u, __ATOMIC_RELEASE,
                                 __HIP_MEMORY_SCOPE_WORKGROUP);
      }
    }
  } else {
    // ============== projection role ==============
    _Float16* pw = (_Float16*)(smem + PW_OFF);
    float* pb = (float*)(smem + PB_OFF);
    const int p = bid - REC_WGS;
    const int pbase = p * 16;
    // stage W_proj frag-major for 16x16x32: lane l holds B[col=l&15][k=(l>>4)*8+j]
    for (int idx = tid; idx < 32 * 64; idx += BLK) {
      int f = idx >> 6, l = idx & 63;
      int col = pbase + (l & 15);
      int k0 = f * 32 + (l >> 4) * 8;
      _Float16* dst = pw + f * 512 + l * 8;
      #pragma unroll
      for (int j = 0; j < 8; ++j) dst[j] = (_Float16)W_proj[(size_t)(k0 + j) * ODIM + col];
    }
    if (tid < 16) pb[tid] = b_proj[pbase + tid];
    __syncthreads();

    const int tp = w >> 2, nb = (w >> 1) & 1, rh = w & 1;
    const int rowbase = nb * 32 + rh * 16;
    const int arow = rowbase + (lane & 15);
    const int kg = (lane >> 4) * 8;
    const float bz = pb[lane & 15];

    for (int t = tp; t < T_LEN; t += 2) {
      if (lane == 0)
        while (__hip_atomic_load(&cnt[nb * T_LEN + t], __ATOMIC_RELAXED,
                                 __HIP_MEMORY_SCOPE_AGENT) < (unsigned)REC_WGS)
          __builtin_amdgcn_s_sleep(4);
      __asm__ volatile("" ::: "memory");

      f32x4 acc = {};
      const _Float16* hr = hb + (size_t)(t & 7) * HSLOT + (size_t)arow * HID + kg;
      #pragma unroll 8
      for (int i = 0; i < 32; ++i) {
        U16B u;
        u.u[0] = __hip_atomic_load((const unsigned long long*)(hr + i * 32),
                                   __ATOMIC_RELAXED, __HIP_MEMORY_SCOPE_AGENT);
        u.u[1] = __hip_atomic_load((const unsigned long long*)(hr + i * 32 + 4),
                                   __ATOMIC_RELAXED, __HIP_MEMORY_SCOPE_AGENT);
        half8 b = *(const half8*)(pw + i * 512 + lane * 8);
        acc = __builtin_amdgcn_mfma_f32_16x16x32_f16(u.h, b, acc, 0, 0, 0);
      }
      #pragma unroll
      for (int r = 0; r < 4; ++r) {
        int nn = rowbase + (lane >> 4) * 4 + r;
        out[((size_t)nn * T_LEN + t) * ODIM + pbase + (lane & 15)] = acc[r] + bz;
      }
    }
  }
}

extern "C" void kernel_launch(void* const* d_in, const int* in_sizes, int n_in,
                              void* d_out, int out_size, void* d_ws, size_t ws_size,
                              hipStream_t stream) {
  const float* obs    = (const float*)d_in[0];
  const float* h0     = (const float*)d_in[1];
  const float* c0     = (const float*)d_in[2];
  const float* es     = (const float*)d_in[3];
  const float* W_ih   = (const float*)d_in[4];
  const float* W_hh   = (const float*)d_in[5];
  const float* b_ih   = (const float*)d_in[6];
  const float* b_hh   = (const float*)d_in[7];
  const float* W_proj = (const float*)d_in[8];
  const float* b_proj = (const float*)d_in[9];
  float* out = (float*)d_out;
  unsigned char* ws = (unsigned char*)d_ws;

  hipLaunchKernelGGL(init_kernel, dim3(64), dim3(256), 0, stream, h0, ws);

  hipFuncSetAttribute((const void*)lstm_coop,
                      hipFuncAttributeMaxDynamicSharedMemorySize, LDS_BYTES);

  void* args[] = { (void*)&obs, (void*)&c0, (void*)&es, (void*)&W_ih, (void*)&W_hh,
                   (void*)&b_ih, (void*)&b_hh, (void*)&W_proj, (void*)&b_proj,
                   (void*)&out, (void*)&ws };
  hipLaunchCooperativeKernel((const void*)lstm_coop, dim3(TOT_WGS), dim3(BLK),
                             args, LDS_BYTES, stream);
}

// Round 6
// 8497.704 us; speedup vs baseline: 1.4647x; 1.4647x over previous
//
#include <hip/hip_runtime.h>

// ---------------- problem dims ----------------
#define N_SEQ 64
#define T_LEN 512
#define IN_SZ 512
#define HID   1024
#define ODIM  256

// ---------------- config ----------------
#define REC_WGS  128
#define PROJ_WGS 16
#define TOT_WGS  (REC_WGS + PROJ_WGS)
#define BLK      256
#define HSLOT    (N_SEQ * HID)      // halves per ring slot

// ws layout: int arr[2][128] @ 0 ; int arrp[64] @ 1024 B ; ring at HBUF_OFF
#define HBUF_OFF 4096               // fp16 hb[8][64][1024] = 1 MiB

// ---------------- rec LDS layout (bytes, dynamic) ----------------
#define WF_OFF   0                  // 96 frags x 1024 B (frag-major Wi|Wh)
#define CB_OFF   98304              // f32 cbuf[2][1024]  (8192 B)
#define GB_OFF   106496             // f32 gbuf[2][1056]  (8448 B)
#define BIAS_OFF 114944             // f32[32]
#define LFLG_OFF 115072             // int[2]
#define LDS_BYTES 115200
// proj overlay
#define PWF_OFF 0                   // 32 frags x 1024 B
#define PB_OFF  32768               // f32[16]

typedef _Float16 half8  __attribute__((ext_vector_type(8)));
typedef float    f32x4  __attribute__((ext_vector_type(4)));
typedef float    f32x16 __attribute__((ext_vector_type(16)));

union U16B { unsigned long long u[2]; half8 h; };
union U8B  { _Float16 h[4]; unsigned long long u; };

__device__ __forceinline__ float sigmf(float x) { return 1.f / (1.f + expf(-x)); }

__device__ __forceinline__ half8 cvt8(const float* p) {
  f32x4 v0 = *(const f32x4*)p;
  f32x4 v1 = *(const f32x4*)(p + 4);
  half8 h;
  h[0] = (_Float16)v0[0]; h[1] = (_Float16)v0[1];
  h[2] = (_Float16)v0[2]; h[3] = (_Float16)v0[3];
  h[4] = (_Float16)v1[0]; h[5] = (_Float16)v1[1];
  h[6] = (_Float16)v1[2]; h[7] = (_Float16)v1[3];
  return h;
}

#define ALOAD8(p) __hip_atomic_load((const unsigned long long*)(p), __ATOMIC_RELAXED, __HIP_MEMORY_SCOPE_AGENT)
#define ALOAD4(p) __hip_atomic_load((const int*)(p), __ATOMIC_RELAXED, __HIP_MEMORY_SCOPE_AGENT)

// stage 8 h-fragments (16 B each via 2x 8B agent loads)
#define HLOAD(st, f0) { _Pragma("unroll") for (int i_ = 0; i_ < 8; ++i_) { \
    st[2*i_]     = ALOAD8(hrr + ((f0) + i_) * 16); \
    st[2*i_ + 1] = ALOAD8(hrr + ((f0) + i_) * 16 + 4); } }
// consume 8 staged fragments; B-frag (fb+f0+i) read from LDS (frag-major)
#define HMFMA(st, f0, fb) { _Pragma("unroll") for (int i_ = 0; i_ < 8; ++i_) { \
    U16B u_; u_.u[0] = st[2*i_]; u_.u[1] = st[2*i_ + 1]; \
    half8 a_ = u_.h; if (kill) a_ = (half8){}; \
    half8 bv_ = *(const half8*)(wf + ((size_t)((fb) + (f0) + i_) * 64 + lane) * 8); \
    acc = __builtin_amdgcn_mfma_f32_32x32x16_f16(a_, bv_, acc, 0, 0, 0); } }

#define POLL_GE(fl_, tgt_) { for (;;) { \
    int m0_ = ALOAD4((fl_) + lane); \
    int m1_ = ALOAD4((fl_) + 64 + lane); \
    if (__all(min(m0_, m1_) >= (tgt_))) break; \
    __builtin_amdgcn_s_sleep(1); } \
  asm volatile("" ::: "memory"); }

// init: flags = -1, h0 -> ring slot 7
__global__ void init_kernel(const float* __restrict__ h0, unsigned char* __restrict__ ws) {
  int gid = blockIdx.x * 256 + threadIdx.x;
  if (gid < 320) ((int*)ws)[gid] = -1;
  _Float16* h7 = (_Float16*)(ws + HBUF_OFF) + (size_t)7 * HSLOT;
  if (gid < N_SEQ * HID) h7[gid] = (_Float16)h0[gid];
}

__launch_bounds__(BLK, 1)
__global__ void lstm_coop(const float* __restrict__ obs,
                          const float* __restrict__ c0,
                          const float* __restrict__ es,
                          const float* __restrict__ W_ih,
                          const float* __restrict__ W_hh,
                          const float* __restrict__ b_ih,
                          const float* __restrict__ b_hh,
                          const float* __restrict__ W_proj,
                          const float* __restrict__ b_proj,
                          float* __restrict__ out,
                          unsigned char* __restrict__ ws) {
  extern __shared__ char smem[];
  const int tid = threadIdx.x, bid = blockIdx.x;
  const int w = tid >> 6, lane = tid & 63;
  int* arr  = (int*)ws;           // [2][128] chain flags
  int* arrp = (int*)ws + 256;     // [64] proj lag flags
  _Float16* hb = (_Float16*)(ws + HBUF_OFF);

  if (bid < REC_WGS) {
    // ================= recurrent role =================
    const int wg = bid;
    _Float16* wf = (_Float16*)(smem + WF_OFF);
    float* cbuf  = (float*)(smem + CB_OFF);     // [2][1024]
    float* gbuf  = (float*)(smem + GB_OFF);     // [2][1056]
    float* bias  = (float*)(smem + BIAS_OFF);
    int*   lflg  = (int*)(smem + LFLG_OFF);

    // stage Wi|Wh frag-major: frag f covers virtual k = [f*16, f*16+16);
    // lane l holds B[col=l&31][k=f*16+(l>>5)*8+j], 16 B contiguous per lane.
    for (int idx = tid; idx < 96 * 64; idx += BLK) {
      int f = idx >> 6, l = idx & 63;
      int c = l & 31, kg = (l >> 5) * 8;
      int vk = f * 16 + kg;
      int grow = (c >> 3) * HID + wg * 8 + (c & 7);      // < 4096
      const float* src = (vk < IN_SZ)
          ? (W_ih + (size_t)grow * IN_SZ + vk)
          : (W_hh + (size_t)grow * HID + (vk - IN_SZ));
      _Float16* dst = wf + (size_t)idx * 8;
      #pragma unroll
      for (int j = 0; j < 8; ++j) dst[j] = (_Float16)src[j];
    }
    if (tid < 32) {
      int grow = (tid >> 3) * HID + wg * 8 + (tid & 7);
      bias[tid] = b_ih[grow] + b_hh[grow];
    }
    if (tid < 2) lflg[tid] = -1;
    __syncthreads();

    const int ch = w & 1;          // sequence chain (32 seqs)
    const int ks = w >> 1;         // 0 = x + h[0,256) + epilogue, 1 = h[256,1024)
    const int col = lane & 31, kg = (lane >> 5) * 8;
    const int n_a = ch * 32 + col;
    int* fl = arr + ch * 128;

    if (ks == 0) {
      const int erow = lane >> 1, eq = lane & 1;
      const int n_e = ch * 32 + erow;
      const int hcb = wg * 8 + eq * 4;          // < 1024
      float cs[4];
      {
        f32x4 c4 = *(const f32x4*)(c0 + (size_t)n_e * HID + hcb);
        cs[0] = c4[0]; cs[1] = c4[1]; cs[2] = c4[2]; cs[3] = c4[3];
      }
      float* gb = gbuf + ch * 1056;

      for (int t = 0; t < T_LEN; ++t) {
        int ap = (t >= 8) ? ALOAD4(arrp + lane) : 0x7fffffff;
        float esv = es[(size_t)n_a * T_LEN + t];
        bool kill = (esv != 0.f);

        f32x16 acc = {};
        // x part (pre-poll: hides flag discovery; never reset-masked)
        const float* xr = obs + ((size_t)n_a * T_LEN + t) * IN_SZ + kg;
        #pragma unroll
        for (int f = 0; f < 32; ++f) {
          half8 a = cvt8(xr + f * 16);
          half8 bv = *(const half8*)(wf + ((size_t)f * 64 + lane) * 8);
          acc = __builtin_amdgcn_mfma_f32_32x32x16_f16(a, bv, acc, 0, 0, 0);
        }

        if (t > 0) POLL_GE(fl, t - 1);

        // h part k in [0,256): frags 32..47
        const _Float16* hrr = hb + (size_t)((t + 7) & 7) * HSLOT + (size_t)n_a * HID + kg;
        {
          unsigned long long st0[16], st1[16];
          HLOAD(st0, 0) HLOAD(st1, 8)
          HMFMA(st0, 0, 32) HMFMA(st1, 8, 32)
        }

        // combine with ks1 partial
        while (__hip_atomic_load(&lflg[ch], __ATOMIC_ACQUIRE, __HIP_MEMORY_SCOPE_WORKGROUP) < t)
          __builtin_amdgcn_s_sleep(1);
        const float* cbc = cbuf + ch * 1024 + lane * 16;
        float tot[16];
        #pragma unroll
        for (int r = 0; r < 16; ++r) tot[r] = acc[r] + cbc[r];

        // transpose via gbuf (C/D m74: col=lane&31, row=(reg&3)+8*(reg>>2)+4*(lane>>5))
        #pragma unroll
        for (int reg = 0; reg < 16; ++reg) {
          int r = (reg & 3) + 8 * (reg >> 2) + 4 * (lane >> 5);
          gb[r * 33 + col] = tot[reg];
        }
        asm volatile("s_waitcnt lgkmcnt(0)" ::: "memory");

        // epilogue: 32 rows x 8 h-cols over 64 lanes
        float m = 1.f - es[(size_t)n_e * T_LEN + t];
        U8B pk;
        #pragma unroll
        for (int p = 0; p < 4; ++p) {
          int j = eq * 4 + p;
          float pi = gb[erow * 33 + j]      + bias[j];
          float pf = gb[erow * 33 + 8 + j]  + bias[8 + j];
          float pg = gb[erow * 33 + 16 + j] + bias[16 + j];
          float po = gb[erow * 33 + 24 + j] + bias[24 + j];
          float cv = sigmf(pf) * (cs[p] * m) + sigmf(pi) * tanhf(pg);
          cs[p] = cv;
          pk.h[p] = (_Float16)(sigmf(po) * tanhf(cv));
        }

        // ring-reuse guard vs projection (8-deep ring; rarely blocks)
        if (t >= 8) {
          while (!__all(ap >= t - 8)) {
            __builtin_amdgcn_s_sleep(2);
            ap = ALOAD4(arrp + lane);
          }
        }

        // publish h, then flag
        __hip_atomic_store(
            (unsigned long long*)(hb + (size_t)(t & 7) * HSLOT + (size_t)n_e * HID + hcb),
            pk.u, __ATOMIC_RELAXED, __HIP_MEMORY_SCOPE_AGENT);
        asm volatile("s_waitcnt vmcnt(0)" ::: "memory");
        if (lane == 0)
          __hip_atomic_store(fl + wg, t, __ATOMIC_RELAXED, __HIP_MEMORY_SCOPE_AGENT);
      }
    } else {
      // ---------- ks1: h[256,1024) partial, frags 48..95 ----------
      for (int t = 0; t < T_LEN; ++t) {
        float esv = es[(size_t)n_a * T_LEN + t];
        bool kill = (esv != 0.f);
        if (t > 0) POLL_GE(fl, t - 1);

        const _Float16* hrr = hb + (size_t)((t + 7) & 7) * HSLOT +
                              (size_t)n_a * HID + 256 + kg;
        f32x16 acc = {};
        {
          unsigned long long st0[16], st1[16];
          HLOAD(st0, 0)  HLOAD(st1, 8)
          HMFMA(st0, 0, 48)   HLOAD(st0, 16)
          HMFMA(st1, 8, 48)   HLOAD(st1, 24)
          HMFMA(st0, 16, 48)  HLOAD(st0, 32)
          HMFMA(st1, 24, 48)  HLOAD(st1, 40)
          HMFMA(st0, 32, 48)  HMFMA(st1, 40, 48)
        }

        float* cbw = cbuf + ch * 1024 + lane * 16;
        *(f32x4*)(cbw + 0)  = (f32x4){acc[0],  acc[1],  acc[2],  acc[3]};
        *(f32x4*)(cbw + 4)  = (f32x4){acc[4],  acc[5],  acc[6],  acc[7]};
        *(f32x4*)(cbw + 8)  = (f32x4){acc[8],  acc[9],  acc[10], acc[11]};
        *(f32x4*)(cbw + 12) = (f32x4){acc[12], acc[13], acc[14], acc[15]};
        if (lane == 0)
          __hip_atomic_store(&lflg[ch], t, __ATOMIC_RELEASE, __HIP_MEMORY_SCOPE_WORKGROUP);
      }
    }
  } else {
    // ================= projection role =================
    const int p = bid - REC_WGS;
    const int pbase = p * 16;
    _Float16* pwf = (_Float16*)(smem + PWF_OFF);
    float* pb = (float*)(smem + PB_OFF);
    for (int idx = tid; idx < 2048; idx += BLK) {
      int f = idx >> 6, l = idx & 63;
      int colp = pbase + (l & 15);
      int k0 = f * 32 + (l >> 4) * 8;
      _Float16* dst = pwf + (size_t)idx * 8;
      #pragma unroll
      for (int j = 0; j < 8; ++j)
        dst[j] = (_Float16)W_proj[(size_t)(k0 + j) * ODIM + colp];
    }
    if (tid < 16) pb[tid] = b_proj[pbase + tid];
    __syncthreads();

    const int rq = w;                 // row-quarter 0..3
    const int ch = rq >> 1;
    const int n0 = rq * 16;
    const int arow = n0 + (lane & 15);
    const int kg8p = (lane >> 4) * 8;
    const float bz = pb[lane & 15];
    int* fl = arr + ch * 128;

    for (int t = 0; t < T_LEN; ++t) {
      POLL_GE(fl, t);

      const _Float16* hr = hb + (size_t)(t & 7) * HSLOT + (size_t)arow * HID + kg8p;
      f32x4 acc = {};
      unsigned long long st[2][32];
      #pragma unroll
      for (int i = 0; i < 16; ++i) {
        st[0][2*i]     = ALOAD8(hr + i * 32);
        st[0][2*i + 1] = ALOAD8(hr + i * 32 + 4);
      }
      #pragma unroll
      for (int i = 0; i < 16; ++i) {
        st[1][2*i]     = ALOAD8(hr + (16 + i) * 32);
        st[1][2*i + 1] = ALOAD8(hr + (16 + i) * 32 + 4);
      }
      #pragma unroll
      for (int i = 0; i < 16; ++i) {
        U16B u; u.u[0] = st[0][2*i]; u.u[1] = st[0][2*i + 1];
        half8 bv = *(const half8*)(pwf + ((size_t)i * 64 + lane) * 8);
        acc = __builtin_amdgcn_mfma_f32_16x16x32_f16(u.h, bv, acc, 0, 0, 0);
      }
      #pragma unroll
      for (int i = 0; i < 16; ++i) {
        U16B u; u.u[0] = st[1][2*i]; u.u[1] = st[1][2*i + 1];
        half8 bv = *(const half8*)(pwf + ((size_t)(16 + i) * 64 + lane) * 8);
        acc = __builtin_amdgcn_mfma_f32_16x16x32_f16(u.h, bv, acc, 0, 0, 0);
      }
      #pragma unroll
      for (int r = 0; r < 4; ++r) {
        int nn = n0 + (lane >> 4) * 4 + r;
        out[((size_t)nn * T_LEN + t) * ODIM + pbase + (lane & 15)] = acc[r] + bz;
      }
      if (lane == 0)
        __hip_atomic_store(&arrp[p * 4 + w], t, __ATOMIC_RELAXED, __HIP_MEMORY_SCOPE_AGENT);
    }
  }
}

extern "C" void kernel_launch(void* const* d_in, const int* in_sizes, int n_in,
                              void* d_out, int out_size, void* d_ws, size_t ws_size,
                              hipStream_t stream) {
  const float* obs    = (const float*)d_in[0];
  const float* h0     = (const float*)d_in[1];
  const float* c0     = (const float*)d_in[2];
  const float* es     = (const float*)d_in[3];
  const float* W_ih   = (const float*)d_in[4];
  const float* W_hh   = (const float*)d_in[5];
  const float* b_ih   = (const float*)d_in[6];
  const float* b_hh   = (const float*)d_in[7];
  const float* W_proj = (const float*)d_in[8];
  const float* b_proj = (const float*)d_in[9];
  float* out = (float*)d_out;
  unsigned char* ws = (unsigned char*)d_ws;

  hipLaunchKernelGGL(init_kernel, dim3(256), dim3(256), 0, stream, h0, ws);

  hipFuncSetAttribute((const void*)lstm_coop,
                      hipFuncAttributeMaxDynamicSharedMemorySize, LDS_BYTES);

  void* args[] = { (void*)&obs, (void*)&c0, (void*)&es, (void*)&W_ih, (void*)&W_hh,
                   (void*)&b_ih, (void*)&b_hh, (void*)&W_proj, (void*)&b_proj,
                   (void*)&out, (void*)&ws };
  hipLaunchCooperativeKernel((const void*)lstm_coop, dim3(TOT_WGS), dim3(BLK),
                             args, LDS_BYTES, stream);
}

// Round 7
// 8402.903 us; speedup vs baseline: 1.4813x; 1.0113x over previous
//
#include <hip/hip_runtime.h>

// ---------------- problem dims ----------------
#define N_SEQ 64
#define T_LEN 512
#define IN_SZ 512
#define HID   1024
#define ODIM  256

// ---------------- config ----------------
#define REC_WGS  128
#define PROJ_WGS 16
#define TOT_WGS  (REC_WGS + PROJ_WGS)
#define BLK      256
#define HSLOT    (N_SEQ * HID)      // halves per ring slot

// ws layout: int arr[2][128] @ 0 ; int arrp[64] @ 1024 B ; ring at HBUF_OFF
#define HBUF_OFF 4096               // fp16 hb[8][64][1024] = 1 MiB

// ---------------- rec LDS layout (bytes, dynamic) ----------------
#define WF_OFF   0                  // 96 frags x 1024 B (frag-major Wi|Wh)
#define CB_OFF   98304              // f32 cbuf[2][1088] (padded stride 17) 8704 B
#define GB_OFF   107008             // f32 gbuf[2][1056]  (8448 B)
#define BIAS_OFF 115456             // f32[32]
#define LFLG_OFF 115584             // int[2]
#define GSTEP_OFF 115592            // int
#define LDS_BYTES 115712
// proj overlay
#define PWF_OFF 0                   // 32 frags x 1024 B
#define PB_OFF  32768               // f32[16]
#define PGS_OFF 32832               // int

typedef _Float16 half8  __attribute__((ext_vector_type(8)));
typedef float    f32x4  __attribute__((ext_vector_type(4)));
typedef float    f32x16 __attribute__((ext_vector_type(16)));

union U16B { unsigned long long u[2]; half8 h; };
union U8B  { _Float16 h[4]; unsigned long long u; };

__device__ __forceinline__ float sigmf(float x) { return 1.f / (1.f + expf(-x)); }

__device__ __forceinline__ half8 cvt8(const float* p) {
  f32x4 v0 = *(const f32x4*)p;
  f32x4 v1 = *(const f32x4*)(p + 4);
  half8 h;
  h[0] = (_Float16)v0[0]; h[1] = (_Float16)v0[1];
  h[2] = (_Float16)v0[2]; h[3] = (_Float16)v0[3];
  h[4] = (_Float16)v1[0]; h[5] = (_Float16)v1[1];
  h[6] = (_Float16)v1[2]; h[7] = (_Float16)v1[3];
  return h;
}

#define ALOAD8(p) __hip_atomic_load((const unsigned long long*)(p), __ATOMIC_RELAXED, __HIP_MEMORY_SCOPE_AGENT)
#define ALOAD4(p) __hip_atomic_load((const int*)(p), __ATOMIC_RELAXED, __HIP_MEMORY_SCOPE_AGENT)

// stage 8 h-fragments (16 B each via 2x 8B agent loads)
#define HLOAD(st, f0) { _Pragma("unroll") for (int i_ = 0; i_ < 8; ++i_) { \
    st[2*i_]     = ALOAD8(hrr + ((f0) + i_) * 16); \
    st[2*i_ + 1] = ALOAD8(hrr + ((f0) + i_) * 16 + 4); } }
// consume 8 staged fragments; B-frag (fb+f0+i) read from LDS (frag-major)
#define HMFMA(st, f0, fb) { _Pragma("unroll") for (int i_ = 0; i_ < 8; ++i_) { \
    U16B u_; u_.u[0] = st[2*i_]; u_.u[1] = st[2*i_ + 1]; \
    half8 a_ = u_.h; if (kill) a_ = (half8){}; \
    half8 bv_ = *(const half8*)(wf + ((size_t)((fb) + (f0) + i_) * 64 + lane) * 8); \
    acc = __builtin_amdgcn_mfma_f32_32x32x16_f16(a_, bv_, acc, 0, 0, 0); } }

// leader: poll all 256 flags (both chains) for >= tgt
#define LEAD_POLL(tgt_) { for (;;) { \
    int m0_ = ALOAD4(arr + lane); \
    int m1_ = ALOAD4(arr + 64 + lane); \
    int m2_ = ALOAD4(arr + 128 + lane); \
    int m3_ = ALOAD4(arr + 192 + lane); \
    if (__all(min(min(m0_, m1_), min(m2_, m3_)) >= (tgt_))) break; \
    __builtin_amdgcn_s_sleep(1); } \
  asm volatile("" ::: "memory"); }

#define LDS_SPIN(ptr_, tgt_) { \
  while (__hip_atomic_load((ptr_), __ATOMIC_ACQUIRE, __HIP_MEMORY_SCOPE_WORKGROUP) < (tgt_)) {} \
  asm volatile("" ::: "memory"); }

// init: flags = -1, h0 -> ring slot 7
__global__ void init_kernel(const float* __restrict__ h0, unsigned char* __restrict__ ws) {
  int gid = blockIdx.x * 256 + threadIdx.x;
  if (gid < 320) ((int*)ws)[gid] = -1;
  _Float16* h7 = (_Float16*)(ws + HBUF_OFF) + (size_t)7 * HSLOT;
  if (gid < N_SEQ * HID) h7[gid] = (_Float16)h0[gid];
}

__launch_bounds__(BLK, 1)
__global__ void lstm_coop(const float* __restrict__ obs,
                          const float* __restrict__ c0,
                          const float* __restrict__ es,
                          const float* __restrict__ W_ih,
                          const float* __restrict__ W_hh,
                          const float* __restrict__ b_ih,
                          const float* __restrict__ b_hh,
                          const float* __restrict__ W_proj,
                          const float* __restrict__ b_proj,
                          float* __restrict__ out,
                          unsigned char* __restrict__ ws) {
  extern __shared__ char smem[];
  const int tid = threadIdx.x, bid = blockIdx.x;
  const int w = tid >> 6, lane = tid & 63;
  int* arr  = (int*)ws;           // [2][128] chain flags
  int* arrp = (int*)ws + 256;     // [64] proj lag flags
  _Float16* hb = (_Float16*)(ws + HBUF_OFF);

  if (bid < REC_WGS) {
    // ================= recurrent role =================
    const int wg = bid;
    _Float16* wf = (_Float16*)(smem + WF_OFF);
    float* cbuf  = (float*)(smem + CB_OFF);     // [2][1088], lane stride 17
    float* gbuf  = (float*)(smem + GB_OFF);     // [2][1056]
    float* bias  = (float*)(smem + BIAS_OFF);
    int*   lflg  = (int*)(smem + LFLG_OFF);
    int*   gstep = (int*)(smem + GSTEP_OFF);

    // stage Wi|Wh frag-major: frag f covers virtual k = [f*16, f*16+16);
    // lane l holds B[col=l&31][k=f*16+(l>>5)*8+j], 16 B contiguous per lane.
    for (int idx = tid; idx < 96 * 64; idx += BLK) {
      int f = idx >> 6, l = idx & 63;
      int c = l & 31, kg = (l >> 5) * 8;
      int vk = f * 16 + kg;
      int grow = (c >> 3) * HID + wg * 8 + (c & 7);      // < 4096
      const float* src = (vk < IN_SZ)
          ? (W_ih + (size_t)grow * IN_SZ + vk)
          : (W_hh + (size_t)grow * HID + (vk - IN_SZ));
      _Float16* dst = wf + (size_t)idx * 8;
      #pragma unroll
      for (int j = 0; j < 8; ++j) dst[j] = (_Float16)src[j];
    }
    if (tid < 32) {
      int grow = (tid >> 3) * HID + wg * 8 + (tid & 7);
      bias[tid] = b_ih[grow] + b_hh[grow];
    }
    if (tid < 2) lflg[tid] = -1;
    if (tid == 0) *gstep = -1;
    __syncthreads();

    const int ch = w & 1;          // sequence chain (32 seqs)
    const int ks = w >> 1;         // 0 = x + h[0,256) + epilogue, 1 = h[256,1024)
    const int col = lane & 31, kg = (lane >> 5) * 8;
    const int n_a = ch * 32 + col;

    if (ks == 0) {
      const int erow = lane >> 1, eq = lane & 1;
      const int n_e = ch * 32 + erow;
      const int hcb = wg * 8 + eq * 4;          // < 1024
      float cs[4];
      {
        f32x4 c4 = *(const f32x4*)(c0 + (size_t)n_e * HID + hcb);
        cs[0] = c4[0]; cs[1] = c4[1]; cs[2] = c4[2]; cs[3] = c4[3];
      }
      float* gb = gbuf + ch * 1056;

      for (int t = 0; t < T_LEN; ++t) {
        int ap = (t >= 8) ? ALOAD4(arrp + lane) : 0x7fffffff;
        float esv = es[(size_t)n_a * T_LEN + t];
        bool kill = (esv != 0.f);

        f32x16 acc = {};
        // x part (pre-spin: hides flag discovery; never reset-masked)
        const float* xr = obs + ((size_t)n_a * T_LEN + t) * IN_SZ + kg;
        #pragma unroll
        for (int f = 0; f < 32; ++f) {
          half8 a = cvt8(xr + f * 16);
          half8 bv = *(const half8*)(wf + ((size_t)f * 64 + lane) * 8);
          acc = __builtin_amdgcn_mfma_f32_32x32x16_f16(a, bv, acc, 0, 0, 0);
        }

        if (t > 0) LDS_SPIN(gstep, t - 1);

        // h part k in [0,256): frags 32..47
        const _Float16* hrr = hb + (size_t)((t + 7) & 7) * HSLOT + (size_t)n_a * HID + kg;
        {
          unsigned long long st0[16], st1[16];
          HLOAD(st0, 0) HLOAD(st1, 8)
          HMFMA(st0, 0, 32) HMFMA(st1, 8, 32)
        }

        // combine with ks1 partial
        while (__hip_atomic_load(&lflg[ch], __ATOMIC_ACQUIRE, __HIP_MEMORY_SCOPE_WORKGROUP) < t)
          __builtin_amdgcn_s_sleep(0);
        const float* cbc = cbuf + ch * 1088 + lane * 17;
        float tot[16];
        #pragma unroll
        for (int r = 0; r < 16; ++r) tot[r] = acc[r] + cbc[r];

        // transpose via gbuf (C/D m74: col=lane&31, row=(reg&3)+8*(reg>>2)+4*(lane>>5))
        #pragma unroll
        for (int reg = 0; reg < 16; ++reg) {
          int r = (reg & 3) + 8 * (reg >> 2) + 4 * (lane >> 5);
          gb[r * 33 + col] = tot[reg];
        }
        asm volatile("s_waitcnt lgkmcnt(0)" ::: "memory");

        // epilogue: 32 rows x 8 h-cols over 64 lanes
        float m = 1.f - es[(size_t)n_e * T_LEN + t];
        U8B pk;
        #pragma unroll
        for (int p = 0; p < 4; ++p) {
          int j = eq * 4 + p;
          float pi = gb[erow * 33 + j]      + bias[j];
          float pf = gb[erow * 33 + 8 + j]  + bias[8 + j];
          float pg = gb[erow * 33 + 16 + j] + bias[16 + j];
          float po = gb[erow * 33 + 24 + j] + bias[24 + j];
          float cv = sigmf(pf) * (cs[p] * m) + sigmf(pi) * tanhf(pg);
          cs[p] = cv;
          pk.h[p] = (_Float16)(sigmf(po) * tanhf(cv));
        }

        // ring-reuse guard vs projection (8-deep ring; rarely blocks)
        if (t >= 8) {
          while (!__all(ap >= t - 8)) {
            __builtin_amdgcn_s_sleep(2);
            ap = ALOAD4(arrp + lane);
          }
        }

        // publish h, then flag
        __hip_atomic_store(
            (unsigned long long*)(hb + (size_t)(t & 7) * HSLOT + (size_t)n_e * HID + hcb),
            pk.u, __ATOMIC_RELAXED, __HIP_MEMORY_SCOPE_AGENT);
        asm volatile("s_waitcnt vmcnt(0)" ::: "memory");
        if (lane == 0)
          __hip_atomic_store(arr + ch * 128 + wg, t, __ATOMIC_RELAXED, __HIP_MEMORY_SCOPE_AGENT);
      }
    } else {
      // ---------- ks1: h[256,1024) partial, frags 48..95 ----------
      // wave w==2 is the WG's global-flag leader; w==3 spins on LDS.
      for (int t = 0; t < T_LEN; ++t) {
        float esv = es[(size_t)n_a * T_LEN + t];
        bool kill = (esv != 0.f);
        if (t > 0) {
          if (w == 2) {
            LEAD_POLL(t - 1);
            if (lane == 0)
              __hip_atomic_store(gstep, t - 1, __ATOMIC_RELEASE, __HIP_MEMORY_SCOPE_WORKGROUP);
          } else {
            LDS_SPIN(gstep, t - 1);
          }
        }

        const _Float16* hrr = hb + (size_t)((t + 7) & 7) * HSLOT +
                              (size_t)n_a * HID + 256 + kg;
        f32x16 acc = {};
        {
          unsigned long long st0[16], st1[16];
          HLOAD(st0, 0)  HLOAD(st1, 8)
          HMFMA(st0, 0, 48)   HLOAD(st0, 16)
          HMFMA(st1, 8, 48)   HLOAD(st1, 24)
          HMFMA(st0, 16, 48)  HLOAD(st0, 32)
          HMFMA(st1, 24, 48)  HLOAD(st1, 40)
          HMFMA(st0, 32, 48)  HMFMA(st1, 40, 48)
        }

        float* cbw = cbuf + ch * 1088 + lane * 17;
        *(f32x4*)(cbw + 0)  = (f32x4){acc[0],  acc[1],  acc[2],  acc[3]};
        *(f32x4*)(cbw + 4)  = (f32x4){acc[4],  acc[5],  acc[6],  acc[7]};
        *(f32x4*)(cbw + 8)  = (f32x4){acc[8],  acc[9],  acc[10], acc[11]};
        *(f32x4*)(cbw + 12) = (f32x4){acc[12], acc[13], acc[14], acc[15]};
        asm volatile("s_waitcnt lgkmcnt(0)" ::: "memory");
        if (lane == 0)
          __hip_atomic_store(&lflg[ch], t, __ATOMIC_RELEASE, __HIP_MEMORY_SCOPE_WORKGROUP);
      }
    }
  } else {
    // ================= projection role =================
    const int p = bid - REC_WGS;
    const int pbase = p * 16;
    _Float16* pwf = (_Float16*)(smem + PWF_OFF);
    float* pb = (float*)(smem + PB_OFF);
    int* pgstep = (int*)(smem + PGS_OFF);
    for (int idx = tid; idx < 2048; idx += BLK) {
      int f = idx >> 6, l = idx & 63;
      int colp = pbase + (l & 15);
      int k0 = f * 32 + (l >> 4) * 8;
      _Float16* dst = pwf + (size_t)idx * 8;
      #pragma unroll
      for (int j = 0; j < 8; ++j)
        dst[j] = (_Float16)W_proj[(size_t)(k0 + j) * ODIM + colp];
    }
    if (tid < 16) pb[tid] = b_proj[pbase + tid];
    if (tid == 0) *pgstep = -1;
    __syncthreads();

    const int rq = w;                 // row-quarter 0..3
    const int n0 = rq * 16;
    const int arow = n0 + (lane & 15);
    const int kg8p = (lane >> 4) * 8;
    const float bz = pb[lane & 15];

    for (int t = 0; t < T_LEN; ++t) {
      if (w == 0) {
        LEAD_POLL(t);
        if (lane == 0)
          __hip_atomic_store(pgstep, t, __ATOMIC_RELEASE, __HIP_MEMORY_SCOPE_WORKGROUP);
      } else {
        LDS_SPIN(pgstep, t);
      }

      const _Float16* hr = hb + (size_t)(t & 7) * HSLOT + (size_t)arow * HID + kg8p;
      f32x4 acc = {};
      unsigned long long st[2][32];
      #pragma unroll
      for (int i = 0; i < 16; ++i) {
        st[0][2*i]     = ALOAD8(hr + i * 32);
        st[0][2*i + 1] = ALOAD8(hr + i * 32 + 4);
      }
      #pragma unroll
      for (int i = 0; i < 16; ++i) {
        st[1][2*i]     = ALOAD8(hr + (16 + i) * 32);
        st[1][2*i + 1] = ALOAD8(hr + (16 + i) * 32 + 4);
      }
      #pragma unroll
      for (int i = 0; i < 16; ++i) {
        U16B u; u.u[0] = st[0][2*i]; u.u[1] = st[0][2*i + 1];
        half8 bv = *(const half8*)(pwf + ((size_t)i * 64 + lane) * 8);
        acc = __builtin_amdgcn_mfma_f32_16x16x32_f16(u.h, bv, acc, 0, 0, 0);
      }
      #pragma unroll
      for (int i = 0; i < 16; ++i) {
        U16B u; u.u[0] = st[1][2*i]; u.u[1] = st[1][2*i + 1];
        half8 bv = *(const half8*)(pwf + ((size_t)(16 + i) * 64 + lane) * 8);
        acc = __builtin_amdgcn_mfma_f32_16x16x32_f16(u.h, bv, acc, 0, 0, 0);
      }
      #pragma unroll
      for (int r = 0; r < 4; ++r) {
        int nn = n0 + (lane >> 4) * 4 + r;
        out[((size_t)nn * T_LEN + t) * ODIM + pbase + (lane & 15)] = acc[r] + bz;
      }
      if (lane == 0)
        __hip_atomic_store(&arrp[p * 4 + w], t, __ATOMIC_RELAXED, __HIP_MEMORY_SCOPE_AGENT);
    }
  }
}

extern "C" void kernel_launch(void* const* d_in, const int* in_sizes, int n_in,
                              void* d_out, int out_size, void* d_ws, size_t ws_size,
                              hipStream_t stream) {
  const float* obs    = (const float*)d_in[0];
  const float* h0     = (const float*)d_in[1];
  const float* c0     = (const float*)d_in[2];
  const float* es     = (const float*)d_in[3];
  const float* W_ih   = (const float*)d_in[4];
  const float* W_hh   = (const float*)d_in[5];
  const float* b_ih   = (const float*)d_in[6];
  const float* b_hh   = (const float*)d_in[7];
  const float* W_proj = (const float*)d_in[8];
  const float* b_proj = (const float*)d_in[9];
  float* out = (float*)d_out;
  unsigned char* ws = (unsigned char*)d_ws;

  hipLaunchKernelGGL(init_kernel, dim3(256), dim3(256), 0, stream, h0, ws);

  hipFuncSetAttribute((const void*)lstm_coop,
                      hipFuncAttributeMaxDynamicSharedMemorySize, LDS_BYTES);

  void* args[] = { (void*)&obs, (void*)&c0, (void*)&es, (void*)&W_ih, (void*)&W_hh,
                   (void*)&b_ih, (void*)&b_hh, (void*)&W_proj, (void*)&b_proj,
                   (void*)&out, (void*)&ws };
  hipLaunchCooperativeKernel((const void*)lstm_coop, dim3(TOT_WGS), dim3(BLK),
                             args, LDS_BYTES, stream);
}

// Round 8
// 6437.144 us; speedup vs baseline: 1.9336x; 1.3054x over previous
//
#include <hip/hip_runtime.h>

// ---------------- problem dims ----------------
#define N_SEQ 64
#define T_LEN 512
#define IN_SZ 512
#define HID   1024
#define ODIM  256

// ---------------- config ----------------
#define REC_WGS  128
#define PROJ_WGS 16
#define TOT_WGS  (REC_WGS + PROJ_WGS)
#define BLK      256
#define RING_D   64                 // h-ring depth: no address reuse for 64 steps
#define HSLOT    (N_SEQ * HID)      // halves per ring slot

// ws layout: int arr[2][128] @ 0 ; int arrp[64] @ 1024 B ; ring at HBUF_OFF
#define HBUF_OFF 4096               // fp16 hb[64][64][1024] = 8 MiB

// ---------------- rec LDS layout (bytes, dynamic) ----------------
#define WF_OFF   0                  // 96 frags x 1024 B (frag-major Wi|Wh)
#define CB_OFF   98304              // f32 cbuf[2][1088] (padded stride 17) 8704 B
#define GB_OFF   107008             // f32 gbuf[2][1056]  (8448 B)
#define BIAS_OFF 115456             // f32[32]
#define LFLG_OFF 115584             // int[2]
#define GSTEP_OFF 115592            // int
#define LDS_BYTES 115712
// proj overlay
#define PWF_OFF 0                   // 32 frags x 1024 B
#define PB_OFF  32768               // f32[16]
#define PGS_OFF 32832               // int

typedef _Float16 half8  __attribute__((ext_vector_type(8)));
typedef float    f32x4  __attribute__((ext_vector_type(4)));
typedef float    f32x16 __attribute__((ext_vector_type(16)));

union U8B  { _Float16 h[4]; unsigned long long u; };

__device__ __forceinline__ float sigmf(float x) { return 1.f / (1.f + expf(-x)); }

__device__ __forceinline__ half8 cvt8(const float* p) {
  f32x4 v0 = *(const f32x4*)p;
  f32x4 v1 = *(const f32x4*)(p + 4);
  half8 h;
  h[0] = (_Float16)v0[0]; h[1] = (_Float16)v0[1];
  h[2] = (_Float16)v0[2]; h[3] = (_Float16)v0[3];
  h[4] = (_Float16)v1[0]; h[5] = (_Float16)v1[1];
  h[6] = (_Float16)v1[2]; h[7] = (_Float16)v1[3];
  return h;
}

#define ALOAD4(p) __hip_atomic_load((const int*)(p), __ATOMIC_RELAXED, __HIP_MEMORY_SCOPE_AGENT)

// leader: poll all 256 flags (both chains) for >= tgt
#define LEAD_POLL(tgt_) { for (;;) { \
    int m0_ = ALOAD4(arr + lane); \
    int m1_ = ALOAD4(arr + 64 + lane); \
    int m2_ = ALOAD4(arr + 128 + lane); \
    int m3_ = ALOAD4(arr + 192 + lane); \
    if (__all(min(min(m0_, m1_), min(m2_, m3_)) >= (tgt_))) break; \
    __builtin_amdgcn_s_sleep(1); } \
  asm volatile("" ::: "memory"); }

#define LDS_SPIN(ptr_, tgt_) { \
  while (__hip_atomic_load((ptr_), __ATOMIC_ACQUIRE, __HIP_MEMORY_SCOPE_WORKGROUP) < (tgt_)) {} \
  asm volatile("" ::: "memory"); }

// init: flags = -1, h0 -> ring slot RING_D-1
__global__ void init_kernel(const float* __restrict__ h0, unsigned char* __restrict__ ws) {
  int gid = blockIdx.x * 256 + threadIdx.x;
  if (gid < 320) ((int*)ws)[gid] = -1;
  _Float16* hlast = (_Float16*)(ws + HBUF_OFF) + (size_t)(RING_D - 1) * HSLOT;
  if (gid < N_SEQ * HID) hlast[gid] = (_Float16)h0[gid];
}

__launch_bounds__(BLK, 1)
__global__ void lstm_coop(const float* __restrict__ obs,
                          const float* __restrict__ c0,
                          const float* __restrict__ es,
                          const float* __restrict__ W_ih,
                          const float* __restrict__ W_hh,
                          const float* __restrict__ b_ih,
                          const float* __restrict__ b_hh,
                          const float* __restrict__ W_proj,
                          const float* __restrict__ b_proj,
                          float* __restrict__ out,
                          unsigned char* __restrict__ ws) {
  extern __shared__ char smem[];
  const int tid = threadIdx.x, bid = blockIdx.x;
  const int w = tid >> 6, lane = tid & 63;
  int* arr  = (int*)ws;           // [2][128] chain flags
  int* arrp = (int*)ws + 256;     // [64] proj lag flags
  _Float16* hb = (_Float16*)(ws + HBUF_OFF);

  if (bid < REC_WGS) {
    // ================= recurrent role =================
    const int wg = bid;
    _Float16* wf = (_Float16*)(smem + WF_OFF);
    float* cbuf  = (float*)(smem + CB_OFF);     // [2][1088], lane stride 17
    float* gbuf  = (float*)(smem + GB_OFF);     // [2][1056]
    float* bias  = (float*)(smem + BIAS_OFF);
    int*   lflg  = (int*)(smem + LFLG_OFF);
    int*   gstep = (int*)(smem + GSTEP_OFF);

    // stage Wi|Wh frag-major: frag f covers virtual k = [f*16, f*16+16);
    // lane l holds B[col=l&31][k=f*16+(l>>5)*8+j], 16 B contiguous per lane.
    for (int idx = tid; idx < 96 * 64; idx += BLK) {
      int f = idx >> 6, l = idx & 63;
      int c = l & 31, kg = (l >> 5) * 8;
      int vk = f * 16 + kg;
      int grow = (c >> 3) * HID + wg * 8 + (c & 7);      // < 4096
      const float* src = (vk < IN_SZ)
          ? (W_ih + (size_t)grow * IN_SZ + vk)
          : (W_hh + (size_t)grow * HID + (vk - IN_SZ));
      _Float16* dst = wf + (size_t)idx * 8;
      #pragma unroll
      for (int j = 0; j < 8; ++j) dst[j] = (_Float16)src[j];
    }
    if (tid < 32) {
      int grow = (tid >> 3) * HID + wg * 8 + (tid & 7);
      bias[tid] = b_ih[grow] + b_hh[grow];
    }
    if (tid < 2) lflg[tid] = -1;
    if (tid == 0) *gstep = -1;
    __syncthreads();

    const int ch = w & 1;          // sequence chain (32 seqs)
    const int ks = w >> 1;         // 0 = x + h[0,256) + epilogue, 1 = h[256,1024)
    const int col = lane & 31, kg = (lane >> 5) * 8;
    const int n_a = ch * 32 + col;

    if (ks == 0) {
      const int erow = lane >> 1, eq = lane & 1;
      const int n_e = ch * 32 + erow;
      const int hcb = wg * 8 + eq * 4;          // < 1024
      float cs[4];
      {
        f32x4 c4 = *(const f32x4*)(c0 + (size_t)n_e * HID + hcb);
        cs[0] = c4[0]; cs[1] = c4[1]; cs[2] = c4[2]; cs[3] = c4[3];
      }
      float* gb = gbuf + ch * 1056;

      for (int t = 0; t < T_LEN; ++t) {
        int ap = (t >= RING_D) ? ALOAD4(arrp + lane) : 0x7fffffff;
        float esv = es[(size_t)n_a * T_LEN + t];
        bool kill = (esv != 0.f);

        f32x16 acc = {};
        // x part (pre-spin: hides flag discovery; never reset-masked)
        const float* xr = obs + ((size_t)n_a * T_LEN + t) * IN_SZ + kg;
        #pragma unroll
        for (int f = 0; f < 32; ++f) {
          half8 a = cvt8(xr + f * 16);
          half8 bv = *(const half8*)(wf + ((size_t)f * 64 + lane) * 8);
          acc = __builtin_amdgcn_mfma_f32_32x32x16_f16(a, bv, acc, 0, 0, 0);
        }

        if (t > 0) LDS_SPIN(gstep, t - 1);

        // h part k in [0,256): frags 32..47 — PLAIN cached b128 loads
        // (safe: slot address untouched for RING_D steps -> L1/L2 evicted,
        //  fill comes from IC where data provably resides before flag)
        const _Float16* hrr = hb + (size_t)((t + RING_D - 1) & (RING_D - 1)) * HSLOT +
                              (size_t)n_a * HID + kg;
        #pragma unroll
        for (int f = 0; f < 16; ++f) {
          half8 a = *(const half8*)(hrr + f * 16);
          if (kill) a = (half8){};
          half8 bv = *(const half8*)(wf + ((size_t)(32 + f) * 64 + lane) * 8);
          acc = __builtin_amdgcn_mfma_f32_32x32x16_f16(a, bv, acc, 0, 0, 0);
        }

        // combine with ks1 partial
        while (__hip_atomic_load(&lflg[ch], __ATOMIC_ACQUIRE, __HIP_MEMORY_SCOPE_WORKGROUP) < t)
          __builtin_amdgcn_s_sleep(0);
        const float* cbc = cbuf + ch * 1088 + lane * 17;
        float tot[16];
        #pragma unroll
        for (int r = 0; r < 16; ++r) tot[r] = acc[r] + cbc[r];

        // transpose via gbuf (C/D m74: col=lane&31, row=(reg&3)+8*(reg>>2)+4*(lane>>5))
        #pragma unroll
        for (int reg = 0; reg < 16; ++reg) {
          int r = (reg & 3) + 8 * (reg >> 2) + 4 * (lane >> 5);
          gb[r * 33 + col] = tot[reg];
        }
        asm volatile("s_waitcnt lgkmcnt(0)" ::: "memory");

        // epilogue: 32 rows x 8 h-cols over 64 lanes
        float m = 1.f - es[(size_t)n_e * T_LEN + t];
        U8B pk;
        #pragma unroll
        for (int p = 0; p < 4; ++p) {
          int j = eq * 4 + p;
          float pi = gb[erow * 33 + j]      + bias[j];
          float pf = gb[erow * 33 + 8 + j]  + bias[8 + j];
          float pg = gb[erow * 33 + 16 + j] + bias[16 + j];
          float po = gb[erow * 33 + 24 + j] + bias[24 + j];
          float cv = sigmf(pf) * (cs[p] * m) + sigmf(pi) * tanhf(pg);
          cs[p] = cv;
          pk.h[p] = (_Float16)(sigmf(po) * tanhf(cv));
        }

        // ring-reuse guard vs projection (RING_D-deep ring; rarely blocks)
        if (t >= RING_D) {
          while (!__all(ap >= t - RING_D)) {
            __builtin_amdgcn_s_sleep(2);
            ap = ALOAD4(arrp + lane);
          }
        }

        // publish h (sc1, to IC), ack, then flag
        __hip_atomic_store(
            (unsigned long long*)(hb + (size_t)(t & (RING_D - 1)) * HSLOT +
                                  (size_t)n_e * HID + hcb),
            pk.u, __ATOMIC_RELAXED, __HIP_MEMORY_SCOPE_AGENT);
        asm volatile("s_waitcnt vmcnt(0)" ::: "memory");
        if (lane == 0)
          __hip_atomic_store(arr + ch * 128 + wg, t, __ATOMIC_RELAXED, __HIP_MEMORY_SCOPE_AGENT);
      }
    } else {
      // ---------- ks1: h[256,1024) partial, frags 48..95 ----------
      // wave w==2 is the WG's global-flag leader; w==3 spins on LDS.
      for (int t = 0; t < T_LEN; ++t) {
        float esv = es[(size_t)n_a * T_LEN + t];
        bool kill = (esv != 0.f);
        if (t > 0) {
          if (w == 2) {
            LEAD_POLL(t - 1);
            if (lane == 0)
              __hip_atomic_store(gstep, t - 1, __ATOMIC_RELEASE, __HIP_MEMORY_SCOPE_WORKGROUP);
          } else {
            LDS_SPIN(gstep, t - 1);
          }
        }

        const _Float16* hrr = hb + (size_t)((t + RING_D - 1) & (RING_D - 1)) * HSLOT +
                              (size_t)n_a * HID + 256 + kg;
        f32x16 acc = {};
        #pragma unroll
        for (int f = 0; f < 48; ++f) {
          half8 a = *(const half8*)(hrr + f * 16);
          if (kill) a = (half8){};
          half8 bv = *(const half8*)(wf + ((size_t)(48 + f) * 64 + lane) * 8);
          acc = __builtin_amdgcn_mfma_f32_32x32x16_f16(a, bv, acc, 0, 0, 0);
        }

        float* cbw = cbuf + ch * 1088 + lane * 17;
        *(f32x4*)(cbw + 0)  = (f32x4){acc[0],  acc[1],  acc[2],  acc[3]};
        *(f32x4*)(cbw + 4)  = (f32x4){acc[4],  acc[5],  acc[6],  acc[7]};
        *(f32x4*)(cbw + 8)  = (f32x4){acc[8],  acc[9],  acc[10], acc[11]};
        *(f32x4*)(cbw + 12) = (f32x4){acc[12], acc[13], acc[14], acc[15]};
        asm volatile("s_waitcnt lgkmcnt(0)" ::: "memory");
        if (lane == 0)
          __hip_atomic_store(&lflg[ch], t, __ATOMIC_RELEASE, __HIP_MEMORY_SCOPE_WORKGROUP);
      }
    }
  } else {
    // ================= projection role =================
    const int p = bid - REC_WGS;
    const int pbase = p * 16;
    _Float16* pwf = (_Float16*)(smem + PWF_OFF);
    float* pb = (float*)(smem + PB_OFF);
    int* pgstep = (int*)(smem + PGS_OFF);
    for (int idx = tid; idx < 2048; idx += BLK) {
      int f = idx >> 6, l = idx & 63;
      int colp = pbase + (l & 15);
      int k0 = f * 32 + (l >> 4) * 8;
      _Float16* dst = pwf + (size_t)idx * 8;
      #pragma unroll
      for (int j = 0; j < 8; ++j)
        dst[j] = (_Float16)W_proj[(size_t)(k0 + j) * ODIM + colp];
    }
    if (tid < 16) pb[tid] = b_proj[pbase + tid];
    if (tid == 0) *pgstep = -1;
    __syncthreads();

    const int rq = w;                 // row-quarter 0..3
    const int n0 = rq * 16;
    const int arow = n0 + (lane & 15);
    const int kg8p = (lane >> 4) * 8;
    const float bz = pb[lane & 15];

    for (int t = 0; t < T_LEN; ++t) {
      if (w == 0) {
        LEAD_POLL(t);
        if (lane == 0)
          __hip_atomic_store(pgstep, t, __ATOMIC_RELEASE, __HIP_MEMORY_SCOPE_WORKGROUP);
      } else {
        LDS_SPIN(pgstep, t);
      }

      const _Float16* hr = hb + (size_t)(t & (RING_D - 1)) * HSLOT +
                           (size_t)arow * HID + kg8p;
      f32x4 acc = {};
      #pragma unroll
      for (int i = 0; i < 32; ++i) {
        half8 a = *(const half8*)(hr + i * 32);
        half8 bv = *(const half8*)(pwf + ((size_t)i * 64 + lane) * 8);
        acc = __builtin_amdgcn_mfma_f32_16x16x32_f16(a, bv, acc, 0, 0, 0);
      }
      #pragma unroll
      for (int r = 0; r < 4; ++r) {
        int nn = n0 + (lane >> 4) * 4 + r;
        out[((size_t)nn * T_LEN + t) * ODIM + pbase + (lane & 15)] = acc[r] + bz;
      }
      if (lane == 0)
        __hip_atomic_store(&arrp[p * 4 + w], t, __ATOMIC_RELAXED, __HIP_MEMORY_SCOPE_AGENT);
    }
  }
}

extern "C" void kernel_launch(void* const* d_in, const int* in_sizes, int n_in,
                              void* d_out, int out_size, void* d_ws, size_t ws_size,
                              hipStream_t stream) {
  const float* obs    = (const float*)d_in[0];
  const float* h0     = (const float*)d_in[1];
  const float* c0     = (const float*)d_in[2];
  const float* es     = (const float*)d_in[3];
  const float* W_ih   = (const float*)d_in[4];
  const float* W_hh   = (const float*)d_in[5];
  const float* b_ih   = (const float*)d_in[6];
  const float* b_hh   = (const float*)d_in[7];
  const float* W_proj = (const float*)d_in[8];
  const float* b_proj = (const float*)d_in[9];
  float* out = (float*)d_out;
  unsigned char* ws = (unsigned char*)d_ws;

  hipLaunchKernelGGL(init_kernel, dim3(256), dim3(256), 0, stream, h0, ws);

  hipFuncSetAttribute((const void*)lstm_coop,
                      hipFuncAttributeMaxDynamicSharedMemorySize, LDS_BYTES);

  void* args[] = { (void*)&obs, (void*)&c0, (void*)&es, (void*)&W_ih, (void*)&W_hh,
                   (void*)&b_ih, (void*)&b_hh, (void*)&W_proj, (void*)&b_proj,
                   (void*)&out, (void*)&ws };
  hipLaunchCooperativeKernel((const void*)lstm_coop, dim3(TOT_WGS), dim3(BLK),
                             args, LDS_BYTES, stream);
}

// Round 9
// 6409.746 us; speedup vs baseline: 1.9419x; 1.0043x over previous
//
#include <hip/hip_runtime.h>

// ---------------- problem dims ----------------
#define N_SEQ 64
#define T_LEN 512
#define IN_SZ 512
#define HID   1024
#define ODIM  256

// ---------------- config ----------------
#define REC_WGS  128
#define PROJ_WGS 16
#define TOT_WGS  (REC_WGS + PROJ_WGS)
#define BLK      256
#define RING_D   64                 // h-ring depth: no address reuse for 64 steps
#define HSLOT    (N_SEQ * HID)      // halves per ring slot

// ws layout: int arr[2][128] @ 0 ; int arrp[64] @ 1024 B ; ring at HBUF_OFF
#define HBUF_OFF 4096               // fp16 hb[64][64][1024] = 8 MiB

// ---------------- rec LDS layout (bytes, dynamic) ----------------
#define WF_OFF   0                  // 96 frags x 1024 B (frag-major Wi|Wh)
#define CB_OFF   98304              // f32 cbuf[2][1088] (padded stride 17) 8704 B
#define GB_OFF   107008             // f32 gbuf[2][1056]  (8448 B)
#define BIAS_OFF 115456             // f32[32]
#define LFLG_OFF 115584             // int[2]
#define GSTEP_OFF 115592            // int
#define LDS_BYTES 115712
// proj overlay
#define PWF_OFF 0                   // 32 frags x 1024 B
#define PB_OFF  32768               // f32[16]
#define PGS_OFF 32832               // int

typedef _Float16 half8  __attribute__((ext_vector_type(8)));
typedef float    f32x4  __attribute__((ext_vector_type(4)));
typedef float    f32x16 __attribute__((ext_vector_type(16)));

union U8B  { _Float16 h[4]; unsigned long long u; };

__device__ __forceinline__ float sigmf(float x) { return 1.f / (1.f + expf(-x)); }

__device__ __forceinline__ half8 cvt8(const float* p) {
  f32x4 v0 = *(const f32x4*)p;
  f32x4 v1 = *(const f32x4*)(p + 4);
  half8 h;
  h[0] = (_Float16)v0[0]; h[1] = (_Float16)v0[1];
  h[2] = (_Float16)v0[2]; h[3] = (_Float16)v0[3];
  h[4] = (_Float16)v1[0]; h[5] = (_Float16)v1[1];
  h[6] = (_Float16)v1[2]; h[7] = (_Float16)v1[3];
  return h;
}

#define ALOAD4(p) __hip_atomic_load((const int*)(p), __ATOMIC_RELAXED, __HIP_MEMORY_SCOPE_AGENT)

// leader: poll all 256 flags (both chains) for >= tgt
#define LEAD_POLL(tgt_) { for (;;) { \
    int m0_ = ALOAD4(arr + lane); \
    int m1_ = ALOAD4(arr + 64 + lane); \
    int m2_ = ALOAD4(arr + 128 + lane); \
    int m3_ = ALOAD4(arr + 192 + lane); \
    if (__all(min(min(m0_, m1_), min(m2_, m3_)) >= (tgt_))) break; \
    __builtin_amdgcn_s_sleep(1); } \
  asm volatile("" ::: "memory"); }

#define LDS_SPIN(ptr_, tgt_) { \
  while (__hip_atomic_load((ptr_), __ATOMIC_ACQUIRE, __HIP_MEMORY_SCOPE_WORKGROUP) < (tgt_)) {} \
  asm volatile("" ::: "memory"); }

// init: flags = -1, h0 -> ring slot RING_D-1
__global__ void init_kernel(const float* __restrict__ h0, unsigned char* __restrict__ ws) {
  int gid = blockIdx.x * 256 + threadIdx.x;
  if (gid < 320) ((int*)ws)[gid] = -1;
  _Float16* hlast = (_Float16*)(ws + HBUF_OFF) + (size_t)(RING_D - 1) * HSLOT;
  if (gid < N_SEQ * HID) hlast[gid] = (_Float16)h0[gid];
}

__launch_bounds__(BLK, 1)
__global__ void lstm_coop(const float* __restrict__ obs,
                          const float* __restrict__ c0,
                          const float* __restrict__ es,
                          const float* __restrict__ W_ih,
                          const float* __restrict__ W_hh,
                          const float* __restrict__ b_ih,
                          const float* __restrict__ b_hh,
                          const float* __restrict__ W_proj,
                          const float* __restrict__ b_proj,
                          float* __restrict__ out,
                          unsigned char* __restrict__ ws) {
  extern __shared__ char smem[];
  const int tid = threadIdx.x, bid = blockIdx.x;
  const int w = tid >> 6, lane = tid & 63;
  int* arr  = (int*)ws;           // [2][128] chain flags
  int* arrp = (int*)ws + 256;     // [64] proj lag flags
  _Float16* hb = (_Float16*)(ws + HBUF_OFF);

  if (bid < REC_WGS) {
    // ================= recurrent role =================
    const int wg = bid;
    _Float16* wf = (_Float16*)(smem + WF_OFF);
    float* cbuf  = (float*)(smem + CB_OFF);     // [2][1088], lane stride 17
    float* gbuf  = (float*)(smem + GB_OFF);     // [2][1056]
    float* bias  = (float*)(smem + BIAS_OFF);
    int*   lflg  = (int*)(smem + LFLG_OFF);
    int*   gstep = (int*)(smem + GSTEP_OFF);

    // stage Wi|Wh frag-major: frag f covers virtual k = [f*16, f*16+16);
    // lane l holds B[col=l&31][k=f*16+(l>>5)*8+j], 16 B contiguous per lane.
    for (int idx = tid; idx < 96 * 64; idx += BLK) {
      int f = idx >> 6, l = idx & 63;
      int c = l & 31, kg = (l >> 5) * 8;
      int vk = f * 16 + kg;
      int grow = (c >> 3) * HID + wg * 8 + (c & 7);      // < 4096
      const float* src = (vk < IN_SZ)
          ? (W_ih + (size_t)grow * IN_SZ + vk)
          : (W_hh + (size_t)grow * HID + (vk - IN_SZ));
      _Float16* dst = wf + (size_t)idx * 8;
      #pragma unroll
      for (int j = 0; j < 8; ++j) dst[j] = (_Float16)src[j];
    }
    if (tid < 32) {
      int grow = (tid >> 3) * HID + wg * 8 + (tid & 7);
      bias[tid] = b_ih[grow] + b_hh[grow];
    }
    if (tid < 2) lflg[tid] = -1;
    if (tid == 0) *gstep = -1;
    __syncthreads();

    const int ch = w & 1;          // sequence chain (32 seqs)
    const int ks = w >> 1;         // 0 = x + h[0,256) + epilogue, 1 = h[256,1024)
    const int col = lane & 31, kg = (lane >> 5) * 8;
    const int n_a = ch * 32 + col;

    if (ks == 0) {
      const int erow = lane >> 1, eq = lane & 1;
      const int n_e = ch * 32 + erow;
      const int hcb = wg * 8 + eq * 4;          // < 1024
      float cs[4];
      {
        f32x4 c4 = *(const f32x4*)(c0 + (size_t)n_e * HID + hcb);
        cs[0] = c4[0]; cs[1] = c4[1]; cs[2] = c4[2]; cs[3] = c4[3];
      }
      float* gb = gbuf + ch * 1056;

      for (int t = 0; t < T_LEN; ++t) {
        int ap = (t >= RING_D) ? ALOAD4(arrp + lane) : 0x7fffffff;
        float esv = es[(size_t)n_a * T_LEN + t];
        bool kill = (esv != 0.f);

        f32x16 acc = {};
        // x part (pre-spin: hides flag discovery; never reset-masked)
        const float* xr = obs + ((size_t)n_a * T_LEN + t) * IN_SZ + kg;
        #pragma unroll
        for (int f = 0; f < 32; ++f) {
          half8 a = cvt8(xr + f * 16);
          half8 bv = *(const half8*)(wf + ((size_t)f * 64 + lane) * 8);
          acc = __builtin_amdgcn_mfma_f32_32x32x16_f16(a, bv, acc, 0, 0, 0);
        }

        if (t > 0) LDS_SPIN(gstep, t - 1);

        // h part k in [0,256): frags 32..47 — PLAIN cached b128 loads
        // (safe: slot address untouched for RING_D steps -> L1/L2 evicted,
        //  fill comes from IC where data provably resides before flag)
        const _Float16* hrr = hb + (size_t)((t + RING_D - 1) & (RING_D - 1)) * HSLOT +
                              (size_t)n_a * HID + kg;
        #pragma unroll
        for (int f = 0; f < 16; ++f) {
          half8 a = *(const half8*)(hrr + f * 16);
          if (kill) a = (half8){};
          half8 bv = *(const half8*)(wf + ((size_t)(32 + f) * 64 + lane) * 8);
          acc = __builtin_amdgcn_mfma_f32_32x32x16_f16(a, bv, acc, 0, 0, 0);
        }

        // combine with ks1 partial
        while (__hip_atomic_load(&lflg[ch], __ATOMIC_ACQUIRE, __HIP_MEMORY_SCOPE_WORKGROUP) < t)
          __builtin_amdgcn_s_sleep(0);
        const float* cbc = cbuf + ch * 1088 + lane * 17;
        float tot[16];
        #pragma unroll
        for (int r = 0; r < 16; ++r) tot[r] = acc[r] + cbc[r];

        // transpose via gbuf (C/D m74: col=lane&31, row=(reg&3)+8*(reg>>2)+4*(lane>>5))
        #pragma unroll
        for (int reg = 0; reg < 16; ++reg) {
          int r = (reg & 3) + 8 * (reg >> 2) + 4 * (lane >> 5);
          gb[r * 33 + col] = tot[reg];
        }
        asm volatile("s_waitcnt lgkmcnt(0)" ::: "memory");

        // epilogue: 32 rows x 8 h-cols over 64 lanes
        float m = 1.f - es[(size_t)n_e * T_LEN + t];
        U8B pk;
        #pragma unroll
        for (int p = 0; p < 4; ++p) {
          int j = eq * 4 + p;
          float pi = gb[erow * 33 + j]      + bias[j];
          float pf = gb[erow * 33 + 8 + j]  + bias[8 + j];
          float pg = gb[erow * 33 + 16 + j] + bias[16 + j];
          float po = gb[erow * 33 + 24 + j] + bias[24 + j];
          float cv = sigmf(pf) * (cs[p] * m) + sigmf(pi) * tanhf(pg);
          cs[p] = cv;
          pk.h[p] = (_Float16)(sigmf(po) * tanhf(cv));
        }

        // ring-reuse guard vs projection (RING_D-deep ring; rarely blocks)
        if (t >= RING_D) {
          while (!__all(ap >= t - RING_D)) {
            __builtin_amdgcn_s_sleep(2);
            ap = ALOAD4(arrp + lane);
          }
        }

        // publish h (sc1, to IC), ack, then flag
        __hip_atomic_store(
            (unsigned long long*)(hb + (size_t)(t & (RING_D - 1)) * HSLOT +
                                  (size_t)n_e * HID + hcb),
            pk.u, __ATOMIC_RELAXED, __HIP_MEMORY_SCOPE_AGENT);
        asm volatile("s_waitcnt vmcnt(0)" ::: "memory");
        if (lane == 0)
          __hip_atomic_store(arr + ch * 128 + wg, t, __ATOMIC_RELAXED, __HIP_MEMORY_SCOPE_AGENT);
      }
    } else {
      // ---------- ks1: h[256,1024) partial, frags 48..95 ----------
      // wave w==2 is the WG's global-flag leader; w==3 spins on LDS.
      for (int t = 0; t < T_LEN; ++t) {
        float esv = es[(size_t)n_a * T_LEN + t];
        bool kill = (esv != 0.f);
        if (t > 0) {
          if (w == 2) {
            LEAD_POLL(t - 1);
            if (lane == 0)
              __hip_atomic_store(gstep, t - 1, __ATOMIC_RELEASE, __HIP_MEMORY_SCOPE_WORKGROUP);
          } else {
            LDS_SPIN(gstep, t - 1);
          }
        }

        const _Float16* hrr = hb + (size_t)((t + RING_D - 1) & (RING_D - 1)) * HSLOT +
                              (size_t)n_a * HID + 256 + kg;
        f32x16 acc = {};
        #pragma unroll
        for (int f = 0; f < 48; ++f) {
          half8 a = *(const half8*)(hrr + f * 16);
          if (kill) a = (half8){};
          half8 bv = *(const half8*)(wf + ((size_t)(48 + f) * 64 + lane) * 8);
          acc = __builtin_amdgcn_mfma_f32_32x32x16_f16(a, bv, acc, 0, 0, 0);
        }

        float* cbw = cbuf + ch * 1088 + lane * 17;
        *(f32x4*)(cbw + 0)  = (f32x4){acc[0],  acc[1],  acc[2],  acc[3]};
        *(f32x4*)(cbw + 4)  = (f32x4){acc[4],  acc[5],  acc[6],  acc[7]};
        *(f32x4*)(cbw + 8)  = (f32x4){acc[8],  acc[9],  acc[10], acc[11]};
        *(f32x4*)(cbw + 12) = (f32x4){acc[12], acc[13], acc[14], acc[15]};
        asm volatile("s_waitcnt lgkmcnt(0)" ::: "memory");
        if (lane == 0)
          __hip_atomic_store(&lflg[ch], t, __ATOMIC_RELEASE, __HIP_MEMORY_SCOPE_WORKGROUP);
      }
    }
  } else {
    // ================= projection role =================
    const int p = bid - REC_WGS;
    const int pbase = p * 16;
    _Float16* pwf = (_Float16*)(smem + PWF_OFF);
    float* pb = (float*)(smem + PB_OFF);
    int* pgstep = (int*)(smem + PGS_OFF);
    for (int idx = tid; idx < 2048; idx += BLK) {
      int f = idx >> 6, l = idx & 63;
      int colp = pbase + (l & 15);
      int k0 = f * 32 + (l >> 4) * 8;
      _Float16* dst = pwf + (size_t)idx * 8;
      #pragma unroll
      for (int j = 0; j < 8; ++j)
        dst[j] = (_Float16)W_proj[(size_t)(k0 + j) * ODIM + colp];
    }
    if (tid < 16) pb[tid] = b_proj[pbase + tid];
    if (tid == 0) *pgstep = -1;
    __syncthreads();

    const int rq = w;                 // row-quarter 0..3
    const int n0 = rq * 16;
    const int arow = n0 + (lane & 15);
    const int kg8p = (lane >> 4) * 8;
    const float bz = pb[lane & 15];

    for (int t = 0; t < T_LEN; ++t) {
      if (w == 0) {
        LEAD_POLL(t);
        if (lane == 0)
          __hip_atomic_store(pgstep, t, __ATOMIC_RELEASE, __HIP_MEMORY_SCOPE_WORKGROUP);
      } else {
        LDS_SPIN(pgstep, t);
      }

      const _Float16* hr = hb + (size_t)(t & (RING_D - 1)) * HSLOT +
                           (size_t)arow * HID + kg8p;
      f32x4 acc = {};
      #pragma unroll
      for (int i = 0; i < 32; ++i) {
        half8 a = *(const half8*)(hr + i * 32);
        half8 bv = *(const half8*)(pwf + ((size_t)i * 64 + lane) * 8);
        acc = __builtin_amdgcn_mfma_f32_16x16x32_f16(a, bv, acc, 0, 0, 0);
      }
      #pragma unroll
      for (int r = 0; r < 4; ++r) {
        int nn = n0 + (lane >> 4) * 4 + r;
        out[((size_t)nn * T_LEN + t) * ODIM + pbase + (lane & 15)] = acc[r] + bz;
      }
      if (lane == 0)
        __hip_atomic_store(&arrp[p * 4 + w], t, __ATOMIC_RELAXED, __HIP_MEMORY_SCOPE_AGENT);
    }
  }
}

extern "C" void kernel_launch(void* const* d_in, const int* in_sizes, int n_in,
                              void* d_out, int out_size, void* d_ws, size_t ws_size,
                              hipStream_t stream) {
  const float* obs    = (const float*)d_in[0];
  const float* h0     = (const float*)d_in[1];
  const float* c0     = (const float*)d_in[2];
  const float* es     = (const float*)d_in[3];
  const float* W_ih   = (const float*)d_in[4];
  const float* W_hh   = (const float*)d_in[5];
  const float* b_ih   = (const float*)d_in[6];
  const float* b_hh   = (const float*)d_in[7];
  const float* W_proj = (const float*)d_in[8];
  const float* b_proj = (const float*)d_in[9];
  float* out = (float*)d_out;
  unsigned char* ws = (unsigned char*)d_ws;

  hipLaunchKernelGGL(init_kernel, dim3(256), dim3(256), 0, stream, h0, ws);

  hipFuncSetAttribute((const void*)lstm_coop,
                      hipFuncAttributeMaxDynamicSharedMemorySize, LDS_BYTES);

  void* args[] = { (void*)&obs, (void*)&c0, (void*)&es, (void*)&W_ih, (void*)&W_hh,
                   (void*)&b_ih, (void*)&b_hh, (void*)&W_proj, (void*)&b_proj,
                   (void*)&out, (void*)&ws };
  hipLaunchCooperativeKernel((const void*)lstm_coop, dim3(TOT_WGS), dim3(BLK),
                             args, LDS_BYTES, stream);
}